// Round 1
// baseline (33755.838 us; speedup 1.0000x reference)
//
#include <hip/hip_runtime.h>
#include <stdint.h>

typedef _Float16 v8hf __attribute__((ext_vector_type(8)));
typedef float v4f __attribute__((ext_vector_type(4)));

__device__ __forceinline__ uint16_t f2h(float f) { _Float16 h = (_Float16)f; uint16_t u; __builtin_memcpy(&u, &h, 2); return u; }
__device__ __forceinline__ float h2f(uint16_t u) { _Float16 h; __builtin_memcpy(&h, &u, 2); return (float)h; }

// 32-block group barrier: monotone counter, release/acquire at device (agent) scope.
__device__ __forceinline__ void group_barrier(unsigned* ctr, unsigned target) {
    __threadfence();
    __syncthreads();
    if (threadIdx.x == 0) {
        __hip_atomic_fetch_add(ctr, 1u, __ATOMIC_RELEASE, __HIP_MEMORY_SCOPE_AGENT);
        long guard = 0;
        while (__hip_atomic_load(ctr, __ATOMIC_ACQUIRE, __HIP_MEMORY_SCOPE_AGENT) < target) {
            __builtin_amdgcn_s_sleep(2);
            if (++guard > 10000000L) break;   // loud failure instead of hang
        }
    }
    __syncthreads();
}

// Stage a [16][512] fp16 tile from global into LDS with XOR swizzle (byte ^= (row&7)<<4).
__device__ __forceinline__ void stage_tile(const uint16_t* __restrict__ src, char* sm, int off) {
    const uint4* s = (const uint4*)src;
    int tid = threadIdx.x;
#pragma unroll
    for (int i = 0; i < 4; ++i) {
        int c16 = i * 256 + tid;            // 16B chunk id, coalesced
        uint4 v = s[c16];
        int byte = c16 << 4;
        int row = byte >> 10;
        int sb = byte ^ ((row & 7) << 4);
        *(uint4*)(sm + off + sb) = v;
    }
}

// lens[b] = sum(mask[b,:]); gmax[group] = max len. Detects bool vs int32 mask layout.
__global__ __launch_bounds__(64) void setup_lens(const void* mask, int* lens, int* gmax) {
    int b = blockIdx.x;
    int lane = threadIdx.x;
    const unsigned char* mp = (const unsigned char*)mask;
    int isbyte = (mp[1] != 0);              // len>=128 => mask[0][1]==1 in byte layout; 0 for int/float
    int cnt = 0;
    if (isbyte) {
        const unsigned char* row = mp + (size_t)b * 512;
        for (int i = lane; i < 512; i += 64) cnt += (row[i] != 0) ? 1 : 0;
    } else {
        const int* row = ((const int*)mask) + (size_t)b * 512;
        for (int i = lane; i < 512; i += 64) cnt += (row[i] != 0) ? 1 : 0;
    }
#pragma unroll
    for (int off = 32; off > 0; off >>= 1) cnt += __shfl_down(cnt, off);
    if (lane == 0) { lens[b] = cnt; atomicMax(&gmax[b >> 4], cnt); }
}

// ---------------- Phase A: layer-0 LSTM + LayerNorm -> h0n (fp16) ----------------
// LDS: [0,64K) WtR0 (transposed fp16, swizzled) | [64K,80K) h tile | [80K,84K) z | [84K..) Wk0/b0 slices
__global__ __launch_bounds__(256, 1) void lstm_phaseA(
    const float* __restrict__ x, const float* __restrict__ Wk0, const float* __restrict__ Wr0,
    const float* __restrict__ b0, const float* __restrict__ gamma, const float* __restrict__ beta,
    const int* __restrict__ lens, const int* __restrict__ gmax,
    unsigned* __restrict__ ctr, uint16_t* __restrict__ hbuf, uint16_t* __restrict__ h0n)
{
    extern __shared__ char sm[];
    const int tid = threadIdx.x;
    const int g = blockIdx.x >> 5;
    const int cs = blockIdx.x & 31;
    const int u0 = cs << 4;                 // this block's 16 units
    const int lane = tid & 63;
    const int wv = tid >> 6;                // wave index == gate index (i,f,g,o)

    // Wr0 slice -> LDS transposed fp16, swizzled: Wt[j][k], j = gate*16+uu
    for (int idx = tid; idx < 512 * 64; idx += 256) {
        int k = idx >> 6, j = idx & 63;
        float v = Wr0[(size_t)k * 2048 + ((j >> 4) << 9) + u0 + (j & 15)];
        int byte = (j << 10) + (k << 1);
        byte ^= ((j & 7) << 4);
        *(uint16_t*)(sm + byte) = f2h(v);
    }
    for (int idx = tid; idx < 192; idx += 256) {
        int f = idx >> 6, j = idx & 63;
        ((float*)(sm + 86016))[idx] = Wk0[(size_t)f * 2048 + ((j >> 4) << 9) + u0 + (j & 15)];
    }
    if (tid < 64) ((float*)(sm + 86784))[tid] = b0[((tid >> 4) << 9) + u0 + (tid & 15)];
    __syncthreads();

    const int r_ep = tid >> 4, q_ep = tid & 15;   // epilogue: thread -> (row, unit)
    const int len_r = lens[(g << 4) + r_ep];
    const int maxlen = gmax[g];
    const float gam = gamma[u0 + q_ep], bet = beta[u0 + q_ep];
    float cstate = 0.f;
    int cur = 0;
    uint16_t* hb = hbuf + (size_t)g * 2 * 8192;
    unsigned* ctrg = ctr + g * 16;

    for (int t = 0;; ++t) {
        stage_tile(hb + (size_t)cur * 8192, sm, 65536);   // h_{t-1} (zeros at t=0 via memset)
        __syncthreads();
        if (t >= 1) {   // LayerNorm h_{t-1} -> h0n[g][t-1]
            float sum = 0.f, ss = 0.f;
#pragma unroll
            for (int c8 = 0; c8 < 4; ++c8) {
                int k = (q_ep << 5) + (c8 << 3);
                int byte = (r_ep << 10) + (k << 1);
                byte ^= ((r_ep & 7) << 4);
                v8hf hv = *(v8hf*)(sm + 65536 + byte);
#pragma unroll
                for (int j = 0; j < 8; ++j) { float f = (float)hv[j]; sum += f; ss += f * f; }
            }
#pragma unroll
            for (int m = 1; m < 16; m <<= 1) { sum += __shfl_xor(sum, m); ss += __shfl_xor(ss, m); }
            float mu = sum * (1.f / 512.f);
            float rstd = rsqrtf(ss * (1.f / 512.f) - mu * mu + 1e-3f);
            int byte = (r_ep << 10) + ((u0 + q_ep) << 1);
            byte ^= ((r_ep & 7) << 4);
            float hv = h2f(*(uint16_t*)(sm + 65536 + byte));
            h0n[(((size_t)g * 512 + (t - 1)) * 16 + r_ep) * 512 + u0 + q_ep] = f2h((hv - mu) * rstd * gam + bet);
        }
        if (t == maxlen) break;
        {   // z[gate wv] = h_{t-1} @ WtR  (M=16,N=16,K=512)
            int rr = lane & 15;
            int kb = (lane >> 4) << 3;
            v4f acc = {0.f, 0.f, 0.f, 0.f};
#pragma unroll
            for (int kk = 0; kk < 16; ++kk) {
                int k = kb + (kk << 5);
                int ab = (rr << 10) + (k << 1); ab ^= ((rr & 7) << 4);
                v8hf a = *(v8hf*)(sm + 65536 + ab);
                int jr = (wv << 4) + rr;
                int bb = (jr << 10) + (k << 1); bb ^= ((jr & 7) << 4);
                v8hf b = *(v8hf*)(sm + bb);
                acc = __builtin_amdgcn_mfma_f32_16x16x32_f16(a, b, acc, 0, 0, 0);
            }
            int mb = ((lane >> 4) << 2), nn = lane & 15;
#pragma unroll
            for (int j = 0; j < 4; ++j)
                *(float*)(sm + 81920 + ((((wv << 4) + mb + j) << 4) + nn) * 4) = acc[j];
        }
        __syncthreads();
        {   // gates + state update (+ zx0 from F=3 input, exact f32)
            const float* xp = x + ((size_t)((g << 4) + r_ep) * 512 + t) * 3;
            float x0 = xp[0], x1 = xp[1], x2 = xp[2];
            const float* wk = (const float*)(sm + 86016);
            const float* bb0 = (const float*)(sm + 86784);
            float zg[4];
#pragma unroll
            for (int G = 0; G < 4; ++G) {
                int j = (G << 4) + q_ep;
                float z = *(float*)(sm + 81920 + ((((G << 4) + r_ep) << 4) + q_ep) * 4);
                zg[G] = z + x0 * wk[j] + x1 * wk[64 + j] + x2 * wk[128 + j] + bb0[j];
            }
            float si = 1.f / (1.f + __expf(-zg[0]));
            float sf = 1.f / (1.f + __expf(-zg[1]));
            float tg = tanhf(zg[2]);
            float so = 1.f / (1.f + __expf(-zg[3]));
            float cn = sf * cstate + si * tg;
            float hn = so * tanhf(cn);
            int hob = (r_ep << 10) + ((u0 + q_ep) << 1); hob ^= ((r_ep & 7) << 4);
            float hold = h2f(*(uint16_t*)(sm + 65536 + hob));
            if (t < len_r) cstate = cn; else hn = hold;   // masked: carry h,c
            hb[(size_t)(cur ^ 1) * 8192 + (r_ep << 9) + u0 + q_ep] = f2h(hn);
        }
        group_barrier(ctrg, (unsigned)(32 * (t + 1)));
        cur ^= 1;
    }
}

// ---------------- Phase B: layer-1 LSTM + LN + FC + softmax -> out ----------------
// LDS: [0,64K) WtR1 | [64K,128K) WtK1 | [128K,144K) tile | [144K,148K) z | [148K..) b1
__global__ __launch_bounds__(256, 1) void lstm_phaseB(
    const float* __restrict__ Wk1, const float* __restrict__ Wr1, const float* __restrict__ b1,
    const float* __restrict__ gamma, const float* __restrict__ beta,
    const float* __restrict__ Wfc, const float* __restrict__ bfc,
    const int* __restrict__ lens, const int* __restrict__ gmax,
    unsigned* __restrict__ ctr, uint16_t* __restrict__ hbuf, const uint16_t* __restrict__ h0n,
    float* __restrict__ out)
{
    extern __shared__ char sm[];
    const int tid = threadIdx.x;
    const int g = blockIdx.x >> 5;
    const int cs = blockIdx.x & 31;
    const int u0 = cs << 4;
    const int lane = tid & 63;
    const int wv = tid >> 6;

    for (int idx = tid; idx < 512 * 64; idx += 256) {
        int k = idx >> 6, j = idx & 63;
        size_t col = (size_t)k * 2048 + ((j >> 4) << 9) + u0 + (j & 15);
        int byte = (j << 10) + (k << 1);
        byte ^= ((j & 7) << 4);
        *(uint16_t*)(sm + byte) = f2h(Wr1[col]);
        *(uint16_t*)(sm + 65536 + byte) = f2h(Wk1[col]);
    }
    if (tid < 64) ((float*)(sm + 151552))[tid] = b1[((tid >> 4) << 9) + u0 + (tid & 15)];
    __syncthreads();

    const int r_ep = tid >> 4, q_ep = tid & 15;
    const int len_r = lens[(g << 4) + r_ep];
    const int maxlen = gmax[g];
    float cstate = 0.f;
    int cur = 0;
    uint16_t* hb = hbuf + (size_t)g * 2 * 8192;
    unsigned* ctrg = ctr + g * 16;
    const int rr = lane & 15;
    const int kb = (lane >> 4) << 3;

    for (int t = 0;; ++t) {
        stage_tile(hb + (size_t)cur * 8192, sm, 131072);   // h1_{t-1}
        __syncthreads();
        v8hf afr[16];                                       // A1 frags before tile reuse
#pragma unroll
        for (int kk = 0; kk < 16; ++kk) {
            int k = kb + (kk << 5);
            int ab = (rr << 10) + (k << 1); ab ^= ((rr & 7) << 4);
            afr[kk] = *(v8hf*)(sm + 131072 + ab);
        }
        int hob = (r_ep << 10) + ((u0 + q_ep) << 1); hob ^= ((r_ep & 7) << 4);
        float hold = h2f(*(uint16_t*)(sm + 131072 + hob));
        if (t >= 1 && cs < 16 && r_ep == cs) {   // LN + FC + softmax for row cs at time t-1
            float hv[32]; float sum = 0.f, ss = 0.f;
#pragma unroll
            for (int c8 = 0; c8 < 4; ++c8) {
                int k = (q_ep << 5) + (c8 << 3);
                int byte = (cs << 10) + (k << 1); byte ^= ((cs & 7) << 4);
                v8hf h8 = *(v8hf*)(sm + 131072 + byte);
#pragma unroll
                for (int j = 0; j < 8; ++j) { float f = (float)h8[j]; hv[(c8 << 3) + j] = f; sum += f; ss += f * f; }
            }
#pragma unroll
            for (int m = 1; m < 16; m <<= 1) { sum += __shfl_xor(sum, m); ss += __shfl_xor(ss, m); }
            float mu = sum * (1.f / 512.f);
            float rstd = rsqrtf(ss * (1.f / 512.f) - mu * mu + 1e-3f);
            float p0 = 0, p1 = 0, p2 = 0, p3 = 0, p4 = 0;
#pragma unroll
            for (int j = 0; j < 32; ++j) {
                int u = (q_ep << 5) + j;
                float hn = (hv[j] - mu) * rstd * gamma[u] + beta[u];
                const float* wf = Wfc + u * 5;
                p0 += hn * wf[0]; p1 += hn * wf[1]; p2 += hn * wf[2]; p3 += hn * wf[3]; p4 += hn * wf[4];
            }
#pragma unroll
            for (int m = 1; m < 16; m <<= 1) {
                p0 += __shfl_xor(p0, m); p1 += __shfl_xor(p1, m); p2 += __shfl_xor(p2, m);
                p3 += __shfl_xor(p3, m); p4 += __shfl_xor(p4, m);
            }
            if (q_ep == 0) {
                float l0 = p0 + bfc[0], l1 = p1 + bfc[1], l2 = p2 + bfc[2], l3 = p3 + bfc[3], l4 = p4 + bfc[4];
                float mx = fmaxf(fmaxf(fmaxf(l0, l1), fmaxf(l2, l3)), l4);
                float e0 = __expf(l0 - mx), e1 = __expf(l1 - mx), e2 = __expf(l2 - mx), e3 = __expf(l3 - mx), e4 = __expf(l4 - mx);
                float inv = 1.f / (e0 + e1 + e2 + e3 + e4);
                float* op = out + ((size_t)((g << 4) + cs) * 512 + (t - 1)) * 5;
                op[0] = e0 * inv; op[1] = e1 * inv; op[2] = e2 * inv; op[3] = e3 * inv; op[4] = e4 * inv;
            }
        }
        __syncthreads();
        if (t == maxlen) break;
        stage_tile(h0n + ((size_t)g * 512 + t) * 8192, sm, 131072);   // x1_t = h0n[:,t]
        __syncthreads();
        {
            v4f accR = {0.f, 0.f, 0.f, 0.f}, accK = {0.f, 0.f, 0.f, 0.f};
#pragma unroll
            for (int kk = 0; kk < 16; ++kk) {
                int k = kb + (kk << 5);
                int jr = (wv << 4) + rr;
                int bb = (jr << 10) + (k << 1); bb ^= ((jr & 7) << 4);
                v8hf bR = *(v8hf*)(sm + bb);
                accR = __builtin_amdgcn_mfma_f32_16x16x32_f16(afr[kk], bR, accR, 0, 0, 0);
                int ab = (rr << 10) + (k << 1); ab ^= ((rr & 7) << 4);
                v8hf a2 = *(v8hf*)(sm + 131072 + ab);
                v8hf bK = *(v8hf*)(sm + 65536 + bb);
                accK = __builtin_amdgcn_mfma_f32_16x16x32_f16(a2, bK, accK, 0, 0, 0);
            }
            int mb = ((lane >> 4) << 2), nn = lane & 15;
#pragma unroll
            for (int j = 0; j < 4; ++j)
                *(float*)(sm + 147456 + ((((wv << 4) + mb + j) << 4) + nn) * 4) = accR[j] + accK[j];
        }
        __syncthreads();
        {
            const float* bb1 = (const float*)(sm + 151552);
            float zg[4];
#pragma unroll
            for (int G = 0; G < 4; ++G)
                zg[G] = *(float*)(sm + 147456 + ((((G << 4) + r_ep) << 4) + q_ep) * 4) + bb1[(G << 4) + q_ep];
            float si = 1.f / (1.f + __expf(-zg[0]));
            float sf = 1.f / (1.f + __expf(-zg[1]));
            float tg = tanhf(zg[2]);
            float so = 1.f / (1.f + __expf(-zg[3]));
            float cn = sf * cstate + si * tg;
            float hn = so * tanhf(cn);
            if (t < len_r) cstate = cn; else hn = hold;
            hb[(size_t)(cur ^ 1) * 8192 + (r_ep << 9) + u0 + q_ep] = f2h(hn);
        }
        group_barrier(ctrg, (unsigned)(32 * (t + 1)));
        cur ^= 1;
    }
    // replicate frozen outputs for t >= maxlen (constant per row)
    group_barrier(ctrg, (unsigned)(32 * (maxlen + 1)));
    int total = 16 * (512 - maxlen) * 5;
    for (int idx = cs * 256 + tid; idx < total; idx += 32 * 256) {
        int c = idx % 5; int rem = idx / 5; int r = rem & 15; int dt = rem >> 4;
        size_t base = (size_t)((g << 4) + r) * 512;
        out[(base + maxlen + dt) * 5 + c] = out[(base + maxlen - 1) * 5 + c];
    }
}

extern "C" void kernel_launch(void* const* d_in, const int* in_sizes, int n_in,
                              void* d_out, int out_size, void* d_ws, size_t ws_size,
                              hipStream_t stream) {
    (void)in_sizes; (void)n_in; (void)out_size;
    const float* x     = (const float*)d_in[0];
    const void*  mask  = d_in[1];
    const float* Wk0   = (const float*)d_in[2];
    const float* Wr0   = (const float*)d_in[3];
    const float* b0    = (const float*)d_in[4];
    const float* Wk1   = (const float*)d_in[5];
    const float* Wr1   = (const float*)d_in[6];
    const float* b1    = (const float*)d_in[7];
    const float* gamma = (const float*)d_in[8];
    const float* beta  = (const float*)d_in[9];
    const float* Wfc   = (const float*)d_in[10];
    const float* bfc   = (const float*)d_in[11];
    float* out = (float*)d_out;
    char* ws = (char*)d_ws;
    int* lens       = (int*)(ws);
    int* gmax       = (int*)(ws + 512);
    unsigned* ctrA  = (unsigned*)(ws + 1024);
    unsigned* ctrB  = (unsigned*)(ws + 1536);
    uint16_t* hbufA = (uint16_t*)(ws + 2048);
    uint16_t* hbufB = (uint16_t*)(ws + 264192);
    uint16_t* h0n   = (uint16_t*)(ws + 526336);
    if (ws_size < 67635200) return;   // need ~64.5 MB scratch

    hipFuncSetAttribute((const void*)lstm_phaseA, hipFuncAttributeMaxDynamicSharedMemorySize, 87040);
    hipFuncSetAttribute((const void*)lstm_phaseB, hipFuncAttributeMaxDynamicSharedMemorySize, 151872);
    hipMemsetAsync(ws, 0, 526336, stream);   // lens/gmax/ctrs/hbufs zeroed every call
    setup_lens<<<128, 64, 0, stream>>>(mask, lens, gmax);
    lstm_phaseA<<<256, 256, 87040, stream>>>(x, Wk0, Wr0, b0, gamma, beta, lens, gmax, ctrA, hbufA, h0n);
    lstm_phaseB<<<256, 256, 151872, stream>>>(Wk1, Wr1, b1, gamma, beta, Wfc, bfc, lens, gmax, ctrB, hbufB, h0n, out);
}

// Round 2
// 8316.821 us; speedup vs baseline: 4.0587x; 4.0587x over previous
//
#include <hip/hip_runtime.h>
#include <stdint.h>

typedef _Float16 v8hf __attribute__((ext_vector_type(8)));
typedef float v4f __attribute__((ext_vector_type(4)));

__device__ __forceinline__ uint16_t f2h(float f) { _Float16 h = (_Float16)f; uint16_t u; __builtin_memcpy(&u, &h, 2); return u; }
__device__ __forceinline__ float h2f(uint16_t u) { _Float16 h; __builtin_memcpy(&h, &u, 2); return (float)h; }

// Leader bumps the group counter with RELEASE (one wbl2), after a __syncthreads()
// has drained all waves' stores to L2.
__device__ __forceinline__ void release_add(unsigned* ctr) {
    if (threadIdx.x == 0)
        __hip_atomic_fetch_add(ctr, 1u, __ATOMIC_RELEASE, __HIP_MEMORY_SCOPE_AGENT);
}
// Leader polls with RELAXED agent loads (sc1 read from IC, NO per-iter L2 invalidate),
// then exactly ONE acquire fence; block-wide barrier publishes to all waves.
__device__ __forceinline__ void wait_acquire(unsigned* ctr, unsigned target) {
    if (threadIdx.x == 0) {
        long guard = 0;
        while (__hip_atomic_load(ctr, __ATOMIC_RELAXED, __HIP_MEMORY_SCOPE_AGENT) < target) {
            __builtin_amdgcn_s_sleep(1);
            if (++guard > 100000000L) break;   // loud failure instead of hang
        }
        __builtin_amdgcn_fence(__ATOMIC_ACQUIRE, "agent");
    }
    __syncthreads();
}

// Stage a [16][512] fp16 tile from global into LDS with XOR swizzle (byte ^= (row&7)<<4).
__device__ __forceinline__ void stage_tile(const uint16_t* __restrict__ src, char* sm, int off) {
    const uint4* s = (const uint4*)src;
    int tid = threadIdx.x;
#pragma unroll
    for (int i = 0; i < 4; ++i) {
        int c16 = i * 256 + tid;            // 16B chunk id, coalesced
        uint4 v = s[c16];
        int byte = c16 << 4;
        int row = byte >> 10;
        int sb = byte ^ ((row & 7) << 4);
        *(uint4*)(sm + off + sb) = v;
    }
}

// LayerNorm one row slice from a swizzled LDS tile; thread covers 32 elems, 16-lane reduce.
__device__ __forceinline__ void ln_store(const char* sm, int tileoff, int r_ep, int q_ep,
                                         float gam, float bet, int hob, uint16_t* dst) {
    float sum = 0.f, ss = 0.f;
#pragma unroll
    for (int c8 = 0; c8 < 4; ++c8) {
        int k = (q_ep << 5) + (c8 << 3);
        int byte = ((r_ep << 10) + (k << 1)) ^ ((r_ep & 7) << 4);
        v8hf hv = *(const v8hf*)(sm + tileoff + byte);
#pragma unroll
        for (int j = 0; j < 8; ++j) { float f = (float)hv[j]; sum += f; ss += f * f; }
    }
#pragma unroll
    for (int m = 1; m < 16; m <<= 1) { sum += __shfl_xor(sum, m); ss += __shfl_xor(ss, m); }
    float mu = sum * (1.f / 512.f);
    float rstd = rsqrtf(ss * (1.f / 512.f) - mu * mu + 1e-3f);
    float hv = h2f(*(const uint16_t*)(sm + tileoff + hob));
    *dst = f2h((hv - mu) * rstd * gam + bet);
}

// lens[b] = sum(mask[b,:]); gmax[group] = max len. Detects bool vs int32 mask layout.
__global__ __launch_bounds__(64) void setup_lens(const void* mask, int* lens, int* gmax) {
    int b = blockIdx.x;
    int lane = threadIdx.x;
    const unsigned char* mp = (const unsigned char*)mask;
    int isbyte = (mp[1] != 0);              // len>=128 => mask[0][1]==1 in byte layout; 0 for int/float
    int cnt = 0;
    if (isbyte) {
        const unsigned char* row = mp + (size_t)b * 512;
        for (int i = lane; i < 512; i += 64) cnt += (row[i] != 0) ? 1 : 0;
    } else {
        const int* row = ((const int*)mask) + (size_t)b * 512;
        for (int i = lane; i < 512; i += 64) cnt += (row[i] != 0) ? 1 : 0;
    }
#pragma unroll
    for (int off = 32; off > 0; off >>= 1) cnt += __shfl_down(cnt, off);
    if (lane == 0) { lens[b] = cnt; atomicMax(&gmax[b >> 4], cnt); }
}

// ---------------- Phase A: layer-0 LSTM + LayerNorm -> h0n (fp16) ----------------
// LDS: [0,64K) WtR0 (transposed fp16, swizzled) | [64K,80K) h tile P | [80K,84K) z | [84K..) Wk0/b0
__global__ __launch_bounds__(256, 1) void lstm_phaseA(
    const float* __restrict__ x, const float* __restrict__ Wk0, const float* __restrict__ Wr0,
    const float* __restrict__ b0, const float* __restrict__ gamma, const float* __restrict__ beta,
    const int* __restrict__ lens, const int* __restrict__ gmax,
    unsigned* __restrict__ ctr, uint16_t* __restrict__ hbuf, uint16_t* __restrict__ h0n)
{
    extern __shared__ char sm[];
    const int tid = threadIdx.x;
    const int g  = blockIdx.x & 7;          // XCD-affine group (round-robin dispatch heuristic)
    const int cs = blockIdx.x >> 3;
    const int u0 = cs << 4;                 // this block's 16 units
    const int lane = tid & 63;
    const int wv = tid >> 6;                // wave index == gate index (i,f,g,o)

    // Wr0 slice -> LDS transposed fp16, swizzled: Wt[j][k], j = gate*16+uu
    for (int idx = tid; idx < 512 * 64; idx += 256) {
        int k = idx >> 6, j = idx & 63;
        float v = Wr0[(size_t)k * 2048 + ((j >> 4) << 9) + u0 + (j & 15)];
        int byte = ((j << 10) + (k << 1)) ^ ((j & 7) << 4);
        *(uint16_t*)(sm + byte) = f2h(v);
    }
    for (int idx = tid; idx < 192; idx += 256) {
        int f = idx >> 6, j = idx & 63;
        ((float*)(sm + 86016))[idx] = Wk0[(size_t)f * 2048 + ((j >> 4) << 9) + u0 + (j & 15)];
    }
    if (tid < 64) ((float*)(sm + 86784))[tid] = b0[((tid >> 4) << 9) + u0 + (tid & 15)];

    const int r_ep = tid >> 4, q_ep = tid & 15;
    const int len_r = lens[(g << 4) + r_ep];
    const int maxlen = gmax[g];
    const float gam = gamma[u0 + q_ep], bet = beta[u0 + q_ep];
    float cstate = 0.f;
    int cur = 0;
    uint16_t* hb = hbuf + (size_t)g * 2 * 8192;
    unsigned* ctrg = ctr + g * 16;
    const int rr = lane & 15;
    const int kb = (lane >> 4) << 3;
    const int hob = ((r_ep << 10) + ((u0 + q_ep) << 1)) ^ ((r_ep & 7) << 4);

    stage_tile(hb, sm, 65536);              // P <- zeros (h_{-1})
    __syncthreads();

    float px0 = x[((size_t)((g << 4) + r_ep) * 512) * 3 + 0];
    float px1 = x[((size_t)((g << 4) + r_ep) * 512) * 3 + 1];
    float px2 = x[((size_t)((g << 4) + r_ep) * 512) * 3 + 2];

    for (int t = 0; t < maxlen; ++t) {
        // z[gate wv] = h_{t-1} @ WtR   (M=16,N=16,K=512)
        v4f acc = {0.f, 0.f, 0.f, 0.f};
#pragma unroll
        for (int kk = 0; kk < 16; ++kk) {
            int k = kb + (kk << 5);
            int ab = ((rr << 10) + (k << 1)) ^ ((rr & 7) << 4);
            v8hf a = *(v8hf*)(sm + 65536 + ab);
            int jr = (wv << 4) + rr;
            int bb = ((jr << 10) + (k << 1)) ^ ((jr & 7) << 4);
            v8hf b = *(v8hf*)(sm + bb);
            acc = __builtin_amdgcn_mfma_f32_16x16x32_f16(a, b, acc, 0, 0, 0);
        }
        { int mb = ((lane >> 4) << 2), nn = lane & 15;
#pragma unroll
          for (int j = 0; j < 4; ++j)
              *(float*)(sm + 81920 + ((((wv << 4) + mb + j) << 4) + nn) * 4) = acc[j]; }
        float hold = h2f(*(uint16_t*)(sm + 65536 + hob));
        __syncthreads();
        {   // gates + state update (+ zx0 from F=3 input, exact f32)
            const float* wk = (const float*)(sm + 86016);
            const float* bb0 = (const float*)(sm + 86784);
            float zg[4];
#pragma unroll
            for (int G = 0; G < 4; ++G) {
                int j = (G << 4) + q_ep;
                float z = *(float*)(sm + 81920 + ((((G << 4) + r_ep) << 4) + q_ep) * 4);
                zg[G] = z + px0 * wk[j] + px1 * wk[64 + j] + px2 * wk[128 + j] + bb0[j];
            }
            float si = 1.f / (1.f + __expf(-zg[0]));
            float sf = 1.f / (1.f + __expf(-zg[1]));
            float tg = tanhf(zg[2]);
            float so = 1.f / (1.f + __expf(-zg[3]));
            float cn = sf * cstate + si * tg;
            float hn = so * tanhf(cn);
            if (t < len_r) cstate = cn; else hn = hold;   // masked: carry h,c
            hb[(size_t)(cur ^ 1) * 8192 + (r_ep << 9) + u0 + q_ep] = f2h(hn);
        }
        __syncthreads();                     // drain h stores to L2
        release_add(ctrg);
        // --- off critical path: LN(h_{t-1}) -> h0n[t-1]; prefetch x[t+1] ---
        if (t >= 1)
            ln_store(sm, 65536, r_ep, q_ep, gam, bet, hob,
                     h0n + (((size_t)g * 512 + (t - 1)) * 16 + r_ep) * 512 + u0 + q_ep);
        { int tn = (t + 1 < maxlen) ? t + 1 : t;
          const float* xp = x + ((size_t)((g << 4) + r_ep) * 512 + tn) * 3;
          px0 = xp[0]; px1 = xp[1]; px2 = xp[2]; }
        wait_acquire(ctrg, 32u * (t + 1));
        cur ^= 1;
        stage_tile(hb + (size_t)cur * 8192, sm, 65536);   // P <- h_t
        __syncthreads();
    }
    // final LN: P = h_{maxlen-1} -> h0n[maxlen-1]
    ln_store(sm, 65536, r_ep, q_ep, gam, bet, hob,
             h0n + (((size_t)g * 512 + (maxlen - 1)) * 16 + r_ep) * 512 + u0 + q_ep);
}

// LN + FC + softmax for row cs at time tt (phase B epilogue), reads P tile at 131072.
__device__ __forceinline__ void epilogueB(const char* sm, int g, int cs, int r_ep, int q_ep,
    const float* __restrict__ gamma, const float* __restrict__ beta,
    const float* __restrict__ Wfc, const float* __restrict__ bfc,
    float* __restrict__ out, int tt)
{
    if (cs >= 16 || r_ep != cs) return;
    float hv[32]; float sum = 0.f, ss = 0.f;
#pragma unroll
    for (int c8 = 0; c8 < 4; ++c8) {
        int k = (q_ep << 5) + (c8 << 3);
        int byte = ((cs << 10) + (k << 1)) ^ ((cs & 7) << 4);
        v8hf h8 = *(const v8hf*)(sm + 131072 + byte);
#pragma unroll
        for (int j = 0; j < 8; ++j) { float f = (float)h8[j]; hv[(c8 << 3) + j] = f; sum += f; ss += f * f; }
    }
#pragma unroll
    for (int m = 1; m < 16; m <<= 1) { sum += __shfl_xor(sum, m); ss += __shfl_xor(ss, m); }
    float mu = sum * (1.f / 512.f);
    float rstd = rsqrtf(ss * (1.f / 512.f) - mu * mu + 1e-3f);
    float p0 = 0, p1 = 0, p2 = 0, p3 = 0, p4 = 0;
#pragma unroll
    for (int j = 0; j < 32; ++j) {
        int u = (q_ep << 5) + j;
        float hn = (hv[j] - mu) * rstd * gamma[u] + beta[u];
        const float* wf = Wfc + u * 5;
        p0 += hn * wf[0]; p1 += hn * wf[1]; p2 += hn * wf[2]; p3 += hn * wf[3]; p4 += hn * wf[4];
    }
#pragma unroll
    for (int m = 1; m < 16; m <<= 1) {
        p0 += __shfl_xor(p0, m); p1 += __shfl_xor(p1, m); p2 += __shfl_xor(p2, m);
        p3 += __shfl_xor(p3, m); p4 += __shfl_xor(p4, m);
    }
    if (q_ep == 0) {
        float l0 = p0 + bfc[0], l1 = p1 + bfc[1], l2 = p2 + bfc[2], l3 = p3 + bfc[3], l4 = p4 + bfc[4];
        float mx = fmaxf(fmaxf(fmaxf(l0, l1), fmaxf(l2, l3)), l4);
        float e0 = __expf(l0 - mx), e1 = __expf(l1 - mx), e2 = __expf(l2 - mx), e3 = __expf(l3 - mx), e4 = __expf(l4 - mx);
        float inv = 1.f / (e0 + e1 + e2 + e3 + e4);
        float* op = out + ((size_t)((g << 4) + cs) * 512 + tt) * 5;
        op[0] = e0 * inv; op[1] = e1 * inv; op[2] = e2 * inv; op[3] = e3 * inv; op[4] = e4 * inv;
    }
}

// ---------------- Phase B: layer-1 LSTM + LN + FC + softmax -> out ----------------
// LDS: [0,64K) WtR1 | [64K,128K) WtK1 | [128K,144K) h1 tile P | [144K,148K) z
__global__ __launch_bounds__(256, 1) void lstm_phaseB(
    const float* __restrict__ Wk1, const float* __restrict__ Wr1, const float* __restrict__ b1,
    const float* __restrict__ gamma, const float* __restrict__ beta,
    const float* __restrict__ Wfc, const float* __restrict__ bfc,
    const int* __restrict__ lens, const int* __restrict__ gmax,
    unsigned* __restrict__ ctr, uint16_t* __restrict__ hbuf, const uint16_t* __restrict__ h0n,
    float* __restrict__ out)
{
    extern __shared__ char sm[];
    const int tid = threadIdx.x;
    const int g  = blockIdx.x & 7;
    const int cs = blockIdx.x >> 3;
    const int u0 = cs << 4;
    const int lane = tid & 63;
    const int wv = tid >> 6;

    for (int idx = tid; idx < 512 * 64; idx += 256) {
        int k = idx >> 6, j = idx & 63;
        size_t col = (size_t)k * 2048 + ((j >> 4) << 9) + u0 + (j & 15);
        int byte = ((j << 10) + (k << 1)) ^ ((j & 7) << 4);
        *(uint16_t*)(sm + byte) = f2h(Wr1[col]);
        *(uint16_t*)(sm + 65536 + byte) = f2h(Wk1[col]);
    }
    const int r_ep = tid >> 4, q_ep = tid & 15;
    float breg[4];
#pragma unroll
    for (int G = 0; G < 4; ++G) breg[G] = b1[(G << 9) + u0 + q_ep];
    const int len_r = lens[(g << 4) + r_ep];
    const int maxlen = gmax[g];
    float cstate = 0.f;
    int cur = 0;
    uint16_t* hb = hbuf + (size_t)g * 2 * 8192;
    unsigned* ctrg = ctr + g * 16;
    const int rr = lane & 15;
    const int kb = (lane >> 4) << 3;
    const int hob = ((r_ep << 10) + ((u0 + q_ep) << 1)) ^ ((r_ep & 7) << 4);

    stage_tile(hb, sm, 131072);             // P <- zeros (h1_{-1})
    __syncthreads();

    // h0n A-fragments: global -> VGPR directly (no LDS round trip), prefetched 1 step ahead
    v8hf a2[16];
    {
        const uint16_t* bse = h0n + ((size_t)g * 512 * 16 + rr) * 512 + kb;
#pragma unroll
        for (int kk = 0; kk < 16; ++kk) a2[kk] = *(const v8hf*)(bse + (kk << 5));
    }

    for (int t = 0; t < maxlen; ++t) {
        v4f accR = {0.f, 0.f, 0.f, 0.f}, accK = {0.f, 0.f, 0.f, 0.f};
#pragma unroll
        for (int kk = 0; kk < 16; ++kk) {
            int k = kb + (kk << 5);
            int ab = ((rr << 10) + (k << 1)) ^ ((rr & 7) << 4);
            v8hf aR = *(v8hf*)(sm + 131072 + ab);
            int jr = (wv << 4) + rr;
            int bb = ((jr << 10) + (k << 1)) ^ ((jr & 7) << 4);
            v8hf bR = *(v8hf*)(sm + bb);
            v8hf bK = *(v8hf*)(sm + 65536 + bb);
            accR = __builtin_amdgcn_mfma_f32_16x16x32_f16(aR, bR, accR, 0, 0, 0);
            accK = __builtin_amdgcn_mfma_f32_16x16x32_f16(a2[kk], bK, accK, 0, 0, 0);
        }
        { int mb = ((lane >> 4) << 2), nn = lane & 15;
#pragma unroll
          for (int j = 0; j < 4; ++j)
              *(float*)(sm + 147456 + ((((wv << 4) + mb + j) << 4) + nn) * 4) = accR[j] + accK[j]; }
        float hold = h2f(*(uint16_t*)(sm + 131072 + hob));
        __syncthreads();
        {
            float zg[4];
#pragma unroll
            for (int G = 0; G < 4; ++G)
                zg[G] = *(float*)(sm + 147456 + ((((G << 4) + r_ep) << 4) + q_ep) * 4) + breg[G];
            float si = 1.f / (1.f + __expf(-zg[0]));
            float sf = 1.f / (1.f + __expf(-zg[1]));
            float tg = tanhf(zg[2]);
            float so = 1.f / (1.f + __expf(-zg[3]));
            float cn = sf * cstate + si * tg;
            float hn = so * tanhf(cn);
            if (t < len_r) cstate = cn; else hn = hold;
            hb[(size_t)(cur ^ 1) * 8192 + (r_ep << 9) + u0 + q_ep] = f2h(hn);
        }
        __syncthreads();
        release_add(ctrg);
        // --- off critical path: LN+FC+softmax of h1_{t-1}; prefetch a2[t+1] ---
        if (t >= 1) epilogueB(sm, g, cs, r_ep, q_ep, gamma, beta, Wfc, bfc, out, t - 1);
        { int tn = (t + 1 < maxlen) ? t + 1 : t;
          const uint16_t* bse = h0n + (((size_t)g * 512 + tn) * 16 + rr) * 512 + kb;
#pragma unroll
          for (int kk = 0; kk < 16; ++kk) a2[kk] = *(const v8hf*)(bse + (kk << 5)); }
        wait_acquire(ctrg, 32u * (t + 1));
        cur ^= 1;
        stage_tile(hb + (size_t)cur * 8192, sm, 131072);  // P <- h1_t
        __syncthreads();
    }
    // final epilogue: out[maxlen-1] from P = h1_{maxlen-1}
    epilogueB(sm, g, cs, r_ep, q_ep, gamma, beta, Wfc, bfc, out, maxlen - 1);
    __syncthreads();
    release_add(ctrg);
    wait_acquire(ctrg, 32u * (maxlen + 1));
    // replicate frozen outputs for t >= maxlen (constant per row)
    int total = 16 * (512 - maxlen) * 5;
    for (int idx = cs * 256 + tid; idx < total; idx += 32 * 256) {
        int c = idx % 5; int rem = idx / 5; int r = rem & 15; int dt = rem >> 4;
        size_t base = (size_t)((g << 4) + r) * 512;
        out[(base + maxlen + dt) * 5 + c] = out[(base + maxlen - 1) * 5 + c];
    }
}

extern "C" void kernel_launch(void* const* d_in, const int* in_sizes, int n_in,
                              void* d_out, int out_size, void* d_ws, size_t ws_size,
                              hipStream_t stream) {
    (void)in_sizes; (void)n_in; (void)out_size;
    const float* x     = (const float*)d_in[0];
    const void*  mask  = d_in[1];
    const float* Wk0   = (const float*)d_in[2];
    const float* Wr0   = (const float*)d_in[3];
    const float* b0    = (const float*)d_in[4];
    const float* Wk1   = (const float*)d_in[5];
    const float* Wr1   = (const float*)d_in[6];
    const float* b1    = (const float*)d_in[7];
    const float* gamma = (const float*)d_in[8];
    const float* beta  = (const float*)d_in[9];
    const float* Wfc   = (const float*)d_in[10];
    const float* bfc   = (const float*)d_in[11];
    float* out = (float*)d_out;
    char* ws = (char*)d_ws;
    int* lens       = (int*)(ws);
    int* gmax       = (int*)(ws + 512);
    unsigned* ctrA  = (unsigned*)(ws + 1024);
    unsigned* ctrB  = (unsigned*)(ws + 1536);
    uint16_t* hbufA = (uint16_t*)(ws + 2048);
    uint16_t* hbufB = (uint16_t*)(ws + 264192);
    uint16_t* h0n   = (uint16_t*)(ws + 526336);
    if (ws_size < 67635200) return;   // need ~64.5 MB scratch

    hipFuncSetAttribute((const void*)lstm_phaseA, hipFuncAttributeMaxDynamicSharedMemorySize, 87040);
    hipFuncSetAttribute((const void*)lstm_phaseB, hipFuncAttributeMaxDynamicSharedMemorySize, 151552);
    hipMemsetAsync(ws, 0, 526336, stream);   // lens/gmax/ctrs/hbufs zeroed every call
    setup_lens<<<128, 64, 0, stream>>>(mask, lens, gmax);
    lstm_phaseA<<<256, 256, 87040, stream>>>(x, Wk0, Wr0, b0, gamma, beta, lens, gmax, ctrA, hbufA, h0n);
    lstm_phaseB<<<256, 256, 151552, stream>>>(Wk1, Wr1, b1, gamma, beta, Wfc, bfc, lens, gmax, ctrB, hbufB, h0n, out);
}

// Round 5
// 5667.367 us; speedup vs baseline: 5.9562x; 1.4675x over previous
//
#include <hip/hip_runtime.h>
#include <stdint.h>

typedef _Float16 v8hf __attribute__((ext_vector_type(8)));
typedef float v4f __attribute__((ext_vector_type(4)));

static __device__ __forceinline__ uint16_t f2h(float f){ _Float16 h=(_Float16)f; uint16_t u; __builtin_memcpy(&u,&h,2); return u; }
static __device__ __forceinline__ float h2f(uint16_t u){ _Float16 h; __builtin_memcpy(&h,&u,2); return (float)h; }

// Stage a [16][512] fp16 tile from global into LDS with XOR swizzle (byte ^= (row&7)<<4).
__device__ __forceinline__ void stage_tile(const uint16_t* __restrict__ src, char* sm, int off) {
    const uint4* s = (const uint4*)src;
    int tid = threadIdx.x;
#pragma unroll
    for (int i = 0; i < 4; ++i) {
        int c16 = i * 256 + tid;
        uint4 v = s[c16];
        int byte = c16 << 4;
        int row = byte >> 10;
        int sb = byte ^ ((row & 7) << 4);
        *(uint4*)(sm + off + sb) = v;
    }
}

// lens[b] = sum(mask[b,:]); gmax[group] = max len. Detects bool vs int32 mask layout.
__global__ __launch_bounds__(64) void setup_lens(const void* mask, int* lens, int* gmax) {
    int b = blockIdx.x;
    int lane = threadIdx.x;
    const unsigned char* mp = (const unsigned char*)mask;
    int isbyte = (mp[1] != 0);
    int cnt = 0;
    if (isbyte) {
        const unsigned char* row = mp + (size_t)b * 512;
        for (int i = lane; i < 512; i += 64) cnt += (row[i] != 0) ? 1 : 0;
    } else {
        const int* row = ((const int*)mask) + (size_t)b * 512;
        for (int i = lane; i < 512; i += 64) cnt += (row[i] != 0) ? 1 : 0;
    }
#pragma unroll
    for (int off = 32; off > 0; off >>= 1) cnt += __shfl_down(cnt, off);
    if (lane == 0) { lens[b] = cnt; atomicMax(&gmax[b >> 4], cnt); }
}

#define P0OFF  65536
#define P1OFF  81920
#define PNOFF  98304
#define Z0OFF  114688
#define ZROFF  118784
#define ZKOFF  122880
#define B1OFF  126976
#define WKOFF  127232
#define B0OFF  128000
#define LDSSZ  128256

// Merged persistent kernel: layer-0 step t and layer-1 step t-1 per iteration.
// Layer-1 input = LN(h0[t-1]) computed EXPLICITLY into LDS tile P0N (fp16), so
// fp16 quantization happens on unit-variance values (round-2-proven numerics).
// gamma folded into wK (wkg = gamma.*Wk1); beta term folded into b1s = b1 + beta@Wk1.
__global__ __launch_bounds__(256, 1) void lstm_merged(
    const float* __restrict__ x, const float* __restrict__ Wk0, const float* __restrict__ Wr0,
    const float* __restrict__ b0, const float* __restrict__ Wk1, const float* __restrict__ Wr1,
    const float* __restrict__ b1, const float* __restrict__ gamma, const float* __restrict__ beta,
    const int* __restrict__ lens, const int* __restrict__ gmax,
    unsigned* __restrict__ ctr, unsigned* __restrict__ slots, unsigned* __restrict__ xcds,
    uint16_t* __restrict__ h0buf, uint16_t* __restrict__ h1all)
{
    extern __shared__ char sm[];
    const int tid = threadIdx.x;
    const int lane = tid & 63;
    const int wv = tid >> 6;                 // wave index == gate index (i,f,g,o)
    const int g  = blockIdx.x & 7;           // group (XCD-affine under round-robin dispatch)
    const int cs = blockIdx.x >> 3;          // unit-slice within group
    const int u0 = cs << 4;

    // ---- one-time per-group XCD-locality check (round-2-proven primitives) ----
    __shared__ int sh_fast;
    unsigned xcc;
    asm volatile("s_getreg_b32 %0, hwreg(HW_REG_XCC_ID)" : "=s"(xcc));
    xcc &= 7;
    if (tid == 0) {
        unsigned* xg = xcds + (g << 5);
        __hip_atomic_store(xg + cs, xcc | 256u, __ATOMIC_RELEASE, __HIP_MEMORY_SCOPE_AGENT);
        int same = 0;
        long guard = 0;
        for (;;) {
            int done = 1; same = 1;
            for (int i = 0; i < 32; ++i) {
                unsigned v = __hip_atomic_load(xg + i, __ATOMIC_RELAXED, __HIP_MEMORY_SCOPE_AGENT);
                done &= (v >= 256u);
                same &= (v == (xcc | 256u));
            }
            if (done) break;
            same = 0;
            __builtin_amdgcn_s_sleep(8);
            if (++guard > 40000L) break;    // fall back to agent protocol
        }
        sh_fast = same;
    }
    __syncthreads();
    const int fast = sh_fast;

    const int rr = lane & 15;
    const int hq = lane >> 4;
    const int kb = hq << 3;

    // ---- weights: Wr0 -> LDS (transposed fp16, swizzled); Wr1/(gamma.*Wk1) -> VGPR frags ----
    for (int idx = tid; idx < 512 * 64; idx += 256) {
        int k = idx >> 6, j = idx & 63;
        float v = Wr0[(size_t)k * 2048 + ((j >> 4) << 9) + u0 + (j & 15)];
        int byte = ((j << 10) + (k << 1)) ^ ((j & 7) << 4);
        *(uint16_t*)(sm + byte) = f2h(v);
    }
    for (int idx = tid; idx < 192; idx += 256) {
        int f = idx >> 6, j = idx & 63;
        ((float*)(sm + WKOFF))[idx] = Wk0[(size_t)f * 2048 + ((j >> 4) << 9) + u0 + (j & 15)];
    }
    if (tid < 64) ((float*)(sm + B0OFF))[tid] = b0[((tid >> 4) << 9) + u0 + (tid & 15)];
    for (int i = tid; i < 12288; i += 256) ((uint32_t*)(sm + P0OFF))[i] = 0u;  // zero P0,P1,P0N

    v8hf wR[16], wK[16];
    {
        const int col = (wv << 9) + u0 + rr;
        float sb = 0.f;
#pragma unroll
        for (int kk = 0; kk < 16; ++kk) {
#pragma unroll
            for (int j = 0; j < 8; ++j) {
                int k = (kk << 5) + kb + j;
                float wr = Wr1[(size_t)k * 2048 + col];
                float wk = Wk1[(size_t)k * 2048 + col];
                wR[kk][j] = (_Float16)wr;
                wK[kk][j] = (_Float16)(gamma[k] * wk);
                sb += beta[k] * wk;
            }
        }
        sb += __shfl_xor(sb, 16); sb += __shfl_xor(sb, 32);
        if (lane < 16)
            ((float*)(sm + B1OFF))[(wv << 4) + lane] = b1[(wv << 9) + u0 + lane] + sb;
    }

    const int r_ep = tid >> 4, q_ep = tid & 15;
    const int len_r = lens[(g << 4) + r_ep];
    const int ml = gmax[g];
    unsigned* ctrg  = ctr + (g << 4);              // agent fallback counter (64B-strided)
    unsigned* slotg = slots + (g << 9);            // 32 slots x 64B stride
    uint16_t* h1g = h1all + (size_t)g * 4194304;
    float c0 = 0.f, c1 = 0.f;
    const int hob = ((r_ep << 10) + ((u0 + q_ep) << 1)) ^ ((r_ep & 7) << 4);
    float px0, px1, px2;
    { const float* xp = x + ((size_t)((g << 4) + r_ep) * 512) * 3;
      px0 = xp[0]; px1 = xp[1]; px2 = xp[2]; }
    __syncthreads();

    for (int t = 0;; ++t) {
        // ---- explicit LN of P0 = h0[t-1] -> P0N (fp16, swizzled) ----
        {
            v8hf r8[4];
            float s = 0.f, q2 = 0.f;
#pragma unroll
            for (int c8 = 0; c8 < 4; ++c8) {
                int k = (q_ep << 5) + (c8 << 3);
                int byte = ((r_ep << 10) + (k << 1)) ^ ((r_ep & 7) << 4);
                r8[c8] = *(const v8hf*)(sm + P0OFF + byte);
#pragma unroll
                for (int j = 0; j < 8; ++j) { float f = (float)r8[c8][j]; s += f; q2 += f * f; }
            }
#pragma unroll
            for (int m = 1; m < 16; m <<= 1) { s += __shfl_xor(s, m); q2 += __shfl_xor(q2, m); }
            float smu = s * (1.f / 512.f);
            float srs = rsqrtf(q2 * (1.f / 512.f) - smu * smu + 1e-3f);
#pragma unroll
            for (int c8 = 0; c8 < 4; ++c8) {
                int k = (q_ep << 5) + (c8 << 3);
                int byte = ((r_ep << 10) + (k << 1)) ^ ((r_ep & 7) << 4);
                v8hf nv;
#pragma unroll
                for (int j = 0; j < 8; ++j) nv[j] = (_Float16)(((float)r8[c8][j] - smu) * srs);
                *(v8hf*)(sm + PNOFF + byte) = nv;
            }
        }
        float hold0 = h2f(*(const uint16_t*)(sm + P0OFF + hob));
        float hold1 = h2f(*(const uint16_t*)(sm + P1OFF + hob));
        __syncthreads();                     // P0N visible to all waves

        // ---- 3 MFMA chains: z0 = P0@Wr0, zK = P0N@(g.*Wk1), zR = P1@Wr1 ----
        v4f acc0 = {0,0,0,0}, accK = {0,0,0,0}, accR = {0,0,0,0};
#pragma unroll
        for (int kk = 0; kk < 16; ++kk) {
            int k = kb + (kk << 5);
            int ab = ((rr << 10) + (k << 1)) ^ ((rr & 7) << 4);
            v8hf a0 = *(const v8hf*)(sm + P0OFF + ab);
            int jr = (wv << 4) + rr;
            int bb = ((jr << 10) + (k << 1)) ^ ((jr & 7) << 4);
            v8hf bf = *(const v8hf*)(sm + bb);
            acc0 = __builtin_amdgcn_mfma_f32_16x16x32_f16(a0, bf, acc0, 0, 0, 0);
            v8hf an = *(const v8hf*)(sm + PNOFF + ab);
            accK = __builtin_amdgcn_mfma_f32_16x16x32_f16(an, wK[kk], accK, 0, 0, 0);
            v8hf a1 = *(const v8hf*)(sm + P1OFF + ab);
            accR = __builtin_amdgcn_mfma_f32_16x16x32_f16(a1, wR[kk], accR, 0, 0, 0);
        }
        {
            float* z0f = (float*)(sm + Z0OFF);
            float* zrf = (float*)(sm + ZROFF);
            float* zkf = (float*)(sm + ZKOFF);
            int j = (wv << 4) + rr;
#pragma unroll
            for (int jj = 0; jj < 4; ++jj) {
                int m = (hq << 2) + jj;
                int w = ((m << 6) + j) ^ ((m & 7) << 2);
                z0f[w] = acc0[jj]; zrf[w] = accR[jj]; zkf[w] = accK[jj];
            }
        }
        __syncthreads();

        // ---- gates ----
        const float* b1s = (const float*)(sm + B1OFF);
        const float* wks = (const float*)(sm + WKOFF);
        const float* b0s = (const float*)(sm + B0OFF);
        if (t < ml) {   // layer-0 step t
            float zg[4];
#pragma unroll
            for (int G = 0; G < 4; ++G) {
                int j = (G << 4) + q_ep;
                int w = ((r_ep << 6) + j) ^ ((r_ep & 7) << 2);
                zg[G] = ((const float*)(sm + Z0OFF))[w]
                      + px0 * wks[j] + px1 * wks[64 + j] + px2 * wks[128 + j] + b0s[j];
            }
            float si = 1.f/(1.f+__expf(-zg[0])), sf = 1.f/(1.f+__expf(-zg[1]));
            float tg = tanhf(zg[2]), so = 1.f/(1.f+__expf(-zg[3]));
            float cn = sf * c0 + si * tg;
            float hn = so * tanhf(cn);
            if (t < len_r) c0 = cn; else hn = hold0;
            h0buf[(size_t)((((t + 1) & 1) << 3) + g) * 8192 + (r_ep << 9) + u0 + q_ep] = f2h(hn);
        }
        if (t >= 1) {   // layer-1 step t-1
            float zg[4];
#pragma unroll
            for (int G = 0; G < 4; ++G) {
                int j = (G << 4) + q_ep;
                int w = ((r_ep << 6) + j) ^ ((r_ep & 7) << 2);
                zg[G] = ((const float*)(sm + ZKOFF))[w] + ((const float*)(sm + ZROFF))[w] + b1s[j];
            }
            float si = 1.f/(1.f+__expf(-zg[0])), sf = 1.f/(1.f+__expf(-zg[1]));
            float tg = tanhf(zg[2]), so = 1.f/(1.f+__expf(-zg[3]));
            float cn = sf * c1 + si * tg;
            float hn = so * tanhf(cn);
            if (t - 1 < len_r) c1 = cn; else hn = hold1;
            h1g[(size_t)(t - 1) * 8192 + (r_ep << 9) + u0 + q_ep] = f2h(hn);
        }
        if (t == ml) break;
        __syncthreads();                     // drain all waves' stores (write-through -> L2)

        // ---- release: RMW executes at L2; relaxed = no cache maintenance ----
        if (tid == 0) {
            if (fast) __hip_atomic_fetch_add(slotg + (cs << 4), 1u, __ATOMIC_RELAXED, __HIP_MEMORY_SCOPE_AGENT);
            else      __hip_atomic_fetch_add(ctrg, 1u, __ATOMIC_RELEASE, __HIP_MEMORY_SCOPE_AGENT);
        }
        // off critical path: prefetch x[t+1]
        { int tn = (t + 1 < ml) ? t + 1 : ml - 1;
          const float* xp = x + ((size_t)((g << 4) + r_ep) * 512 + tn) * 3;
          px0 = xp[0]; px1 = xp[1]; px2 = xp[2]; }
        // ---- wait ----
        if (fast) {
            if (tid < 32) {   // poll = agent-relaxed RMW(+0): executes at shared XCD L2
                unsigned tgt = (unsigned)(t + 1);
                long guard = 0;
                for (;;) {
                    unsigned v = __hip_atomic_fetch_add(slotg + (tid << 4), 0u,
                                                        __ATOMIC_RELAXED, __HIP_MEMORY_SCOPE_AGENT);
                    if ((__ballot(v >= tgt) & 0xFFFFFFFFull) == 0xFFFFFFFFull) break;
                    __builtin_amdgcn_s_sleep(1);
                    if (++guard > 400000L) break;
                }
                asm volatile("buffer_inv\n\ts_waitcnt vmcnt(0)" ::: "memory");  // L1-only inv
            }
            __syncthreads();
        } else {
            if (tid == 0) {
                unsigned tgt = 32u * (unsigned)(t + 1);
                long guard = 0;
                while (__hip_atomic_load(ctrg, __ATOMIC_RELAXED, __HIP_MEMORY_SCOPE_AGENT) < tgt) {
                    __builtin_amdgcn_s_sleep(1);
                    if (++guard > 2000000L) break;
                }
                __builtin_amdgcn_fence(__ATOMIC_ACQUIRE, "agent");
            }
            __syncthreads();
        }
        // ---- stage next tiles: P0 <- h0[t], P1 <- h1[t-1] ----
        stage_tile(h0buf + (size_t)((((t + 1) & 1) << 3) + g) * 8192, sm, P0OFF);
        if (t >= 1) stage_tile(h1g + (size_t)(t - 1) * 8192, sm, P1OFF);
        __syncthreads();
    }
}

// Trailing kernel: out[b,t] = softmax(LN(h1[min(t,ml-1)]) @ Wfc + bfc). One wave per (b,t).
__global__ __launch_bounds__(256) void finalize(
    const uint16_t* __restrict__ h1all, const int* __restrict__ gmax,
    const float* __restrict__ gamma, const float* __restrict__ beta,
    const float* __restrict__ Wfc, const float* __restrict__ bfc,
    float* __restrict__ out)
{
    int wv = threadIdx.x >> 6, lane = threadIdx.x & 63;
    int rid = blockIdx.x * 4 + wv;
    int b = rid >> 9, t = rid & 511;
    int g = b >> 4, r = b & 15;
    int ml = gmax[g];
    int ts = t < ml ? t : ml - 1;
    const uint16_t* hp = h1all + (size_t)g * 4194304 + (size_t)ts * 8192 + (r << 9) + (lane << 3);
    v8hf h8 = *(const v8hf*)hp;
    float hv[8]; float s = 0.f, q2 = 0.f;
#pragma unroll
    for (int j = 0; j < 8; ++j) { float f = (float)h8[j]; hv[j] = f; s += f; q2 += f * f; }
#pragma unroll
    for (int m = 1; m < 64; m <<= 1) { s += __shfl_xor(s, m); q2 += __shfl_xor(q2, m); }
    float mu = s * (1.f / 512.f);
    float rstd = rsqrtf(q2 * (1.f / 512.f) - mu * mu + 1e-3f);
    float p0=0,p1=0,p2=0,p3=0,p4=0;
#pragma unroll
    for (int j = 0; j < 8; ++j) {
        int k = (lane << 3) + j;
        float hn = (hv[j] - mu) * rstd * gamma[k] + beta[k];
        const float* wf = Wfc + (size_t)k * 5;
        p0 += hn*wf[0]; p1 += hn*wf[1]; p2 += hn*wf[2]; p3 += hn*wf[3]; p4 += hn*wf[4];
    }
#pragma unroll
    for (int m = 1; m < 64; m <<= 1) {
        p0 += __shfl_xor(p0,m); p1 += __shfl_xor(p1,m); p2 += __shfl_xor(p2,m);
        p3 += __shfl_xor(p3,m); p4 += __shfl_xor(p4,m);
    }
    if (lane == 0) {
        float l0=p0+bfc[0], l1=p1+bfc[1], l2=p2+bfc[2], l3=p3+bfc[3], l4=p4+bfc[4];
        float mx = fmaxf(fmaxf(fmaxf(l0,l1),fmaxf(l2,l3)),l4);
        float e0=__expf(l0-mx), e1=__expf(l1-mx), e2=__expf(l2-mx), e3=__expf(l3-mx), e4=__expf(l4-mx);
        float inv = 1.f/(e0+e1+e2+e3+e4);
        float* op = out + (size_t)rid * 5;
        op[0]=e0*inv; op[1]=e1*inv; op[2]=e2*inv; op[3]=e3*inv; op[4]=e4*inv;
    }
}

extern "C" void kernel_launch(void* const* d_in, const int* in_sizes, int n_in,
                              void* d_out, int out_size, void* d_ws, size_t ws_size,
                              hipStream_t stream) {
    (void)in_sizes; (void)n_in; (void)out_size;
    const float* x     = (const float*)d_in[0];
    const void*  mask  = d_in[1];
    const float* Wk0   = (const float*)d_in[2];
    const float* Wr0   = (const float*)d_in[3];
    const float* b0    = (const float*)d_in[4];
    const float* Wk1   = (const float*)d_in[5];
    const float* Wr1   = (const float*)d_in[6];
    const float* b1    = (const float*)d_in[7];
    const float* gamma = (const float*)d_in[8];
    const float* beta  = (const float*)d_in[9];
    const float* Wfc   = (const float*)d_in[10];
    const float* bfc   = (const float*)d_in[11];
    float* out = (float*)d_out;
    char* ws = (char*)d_ws;
    unsigned* ctr   = (unsigned*)(ws);            // 8 groups x 64B
    unsigned* slots = (unsigned*)(ws + 512);      // 8 x 32 slots x 64B = 16KB
    unsigned* xcds  = (unsigned*)(ws + 16896);    // 8 x 32 u32 = 1KB
    int*      lens  = (int*)(ws + 17920);         // 128 ints
    int*      gmax  = (int*)(ws + 18432);         // 8 ints
    uint16_t* h0buf = (uint16_t*)(ws + 32768);    // 2 x 8 x 16KB = 256KB
    uint16_t* h1all = (uint16_t*)(ws + 294912);   // 8 x 512 x 16KB = 64MB
    if (ws_size < 67403776) return;

    hipFuncSetAttribute((const void*)lstm_merged, hipFuncAttributeMaxDynamicSharedMemorySize, LDSSZ);
    hipMemsetAsync(ws, 0, 32768, stream);   // ctr/slots/xcds/gmax zeroed every call
    setup_lens<<<128, 64, 0, stream>>>(mask, lens, gmax);
    lstm_merged<<<256, 256, LDSSZ, stream>>>(x, Wk0, Wr0, b0, Wk1, Wr1, b1, gamma, beta,
                                             lens, gmax, ctr, slots, xcds, h0buf, h1all);
    finalize<<<16384, 256, 0, stream>>>(h1all, gmax, gamma, beta, Wfc, bfc, out);
}

// Round 7
// 3361.275 us; speedup vs baseline: 10.0426x; 1.6861x over previous
//
#include <hip/hip_runtime.h>
#include <stdint.h>

typedef _Float16 v8hf __attribute__((ext_vector_type(8)));
typedef float v4f __attribute__((ext_vector_type(4)));

static __device__ __forceinline__ uint16_t f2h(float f){ _Float16 h=(_Float16)f; uint16_t u; __builtin_memcpy(&u,&h,2); return u; }
static __device__ __forceinline__ float h2f(uint16_t u){ _Float16 h; __builtin_memcpy(&h,&u,2); return (float)h; }

#define P0OFF  65536
#define P1OFF  81920
#define Z0OFF  98304
#define Z1OFF  102400
#define MSOFF  106496
#define B1OFF  106624
#define WKOFF  106880
#define B0OFF  107648
#define LDSSZ  107904

// Stage a [16][512] fp16 tile via agent-scope (IC-coherent) u64 atomic loads into
// swizzled LDS; optionally fuse per-row LN stats (16-lane shfl reduce, in-wave).
// Thread t covers 64B of row r=t>>4 (chunk q=t&15): no stale-cache exposure at all.
__device__ __forceinline__ void stage_tile_ic(const uint16_t* __restrict__ srcu16, char* sm, int off,
                                              float* muS, float* rsS, int do_stats) {
    const int tid = threadIdx.x;
    const int r = tid >> 4, q = tid & 15;
    const unsigned long long* s = (const unsigned long long*)srcu16 + (tid << 3);
    unsigned long long v[8];
#pragma unroll
    for (int k = 0; k < 8; ++k)
        v[k] = __hip_atomic_load(s + k, __ATOMIC_RELAXED, __HIP_MEMORY_SCOPE_AGENT);
    if (do_stats) {
        float ps = 0.f, pq = 0.f;
#pragma unroll
        for (int k = 0; k < 8; ++k) {
            unsigned long long w = v[k];
#pragma unroll
            for (int h = 0; h < 4; ++h) {
                float f = h2f((uint16_t)(w >> (16 * h)));
                ps += f; pq += f * f;
            }
        }
#pragma unroll
        for (int m = 1; m < 16; m <<= 1) { ps += __shfl_xor(ps, m); pq += __shfl_xor(pq, m); }
        if (q == 0) {
            float mu = ps * (1.f / 512.f);
            muS[r] = mu;
            rsS[r] = rsqrtf(pq * (1.f / 512.f) - mu * mu + 1e-3f);
        }
    }
    const int b0 = tid << 6;                 // byte base: row r * 1024 + q * 64
    const int swz = (r & 7) << 4;
#pragma unroll
    for (int j = 0; j < 4; ++j) {
        unsigned long long a = v[2 * j], b = v[2 * j + 1];
        uint4 u;
        u.x = (unsigned)a; u.y = (unsigned)(a >> 32);
        u.z = (unsigned)b; u.w = (unsigned)(b >> 32);
        *(uint4*)(sm + off + ((b0 + 16 * j) ^ swz)) = u;
    }
}

// lens[b] = sum(mask[b,:]); gmax[group] = max len. Detects bool vs int32 mask layout.
__global__ __launch_bounds__(64) void setup_lens(const void* mask, int* lens, int* gmax) {
    int b = blockIdx.x;
    int lane = threadIdx.x;
    const unsigned char* mp = (const unsigned char*)mask;
    int isbyte = (mp[1] != 0);
    int cnt = 0;
    if (isbyte) {
        const unsigned char* row = mp + (size_t)b * 512;
        for (int i = lane; i < 512; i += 64) cnt += (row[i] != 0) ? 1 : 0;
    } else {
        const int* row = ((const int*)mask) + (size_t)b * 512;
        for (int i = lane; i < 512; i += 64) cnt += (row[i] != 0) ? 1 : 0;
    }
#pragma unroll
    for (int off = 32; off > 0; off >>= 1) cnt += __shfl_down(cnt, off);
    if (lane == 0) { lens[b] = cnt; atomicMax(&gmax[b >> 4], cnt); }
}

// Merged persistent kernel: layer-0 step t and layer-1 step t-1 per iteration.
// Sync = "IC mailbox": h published via agent-relaxed atomic stores (IC-homed),
// flags via agent-relaxed fetch_add, polls via agent-relaxed loads (R2-proven),
// staging via agent-relaxed u64 loads. No fences, no wbL2/invL2, no mode logic.
__global__ __launch_bounds__(256, 1) void lstm_merged(
    const float* __restrict__ x, const float* __restrict__ Wk0, const float* __restrict__ Wr0,
    const float* __restrict__ b0, const float* __restrict__ Wk1, const float* __restrict__ Wr1,
    const float* __restrict__ b1, const float* __restrict__ gamma, const float* __restrict__ beta,
    const int* __restrict__ lens, const int* __restrict__ gmax,
    unsigned* __restrict__ slots, uint16_t* __restrict__ h0buf, uint16_t* __restrict__ h1all)
{
    extern __shared__ char sm[];
    const int tid = threadIdx.x;
    const int lane = tid & 63;
    const int wv = tid >> 6;                 // wave index == gate index (i,f,g,o)
    const int g  = blockIdx.x & 7;           // group (R5-proven mapping)
    const int cs = blockIdx.x >> 3;          // unit-slice within group
    const int u0 = cs << 4;

    const int rr = lane & 15;
    const int hq = lane >> 4;
    const int kb = hq << 3;

    // ---- weights: Wr0 -> LDS (transposed fp16, swizzled); Wr1/(gamma.*Wk1) -> VGPR frags ----
    for (int idx = tid; idx < 512 * 64; idx += 256) {
        int k = idx >> 6, j = idx & 63;
        float v = Wr0[(size_t)k * 2048 + ((j >> 4) << 9) + u0 + (j & 15)];
        int byte = ((j << 10) + (k << 1)) ^ ((j & 7) << 4);
        *(uint16_t*)(sm + byte) = f2h(v);
    }
    for (int idx = tid; idx < 192; idx += 256) {
        int f = idx >> 6, j = idx & 63;
        ((float*)(sm + WKOFF))[idx] = Wk0[(size_t)f * 2048 + ((j >> 4) << 9) + u0 + (j & 15)];
    }
    if (tid < 64) ((float*)(sm + B0OFF))[tid] = b0[((tid >> 4) << 9) + u0 + (tid & 15)];
    for (int i = tid; i < 8192; i += 256) ((uint32_t*)(sm + P0OFF))[i] = 0u;  // zero P0,P1
    float* muS = (float*)(sm + MSOFF);
    float* rsS = muS + 16;
    if (tid < 16) { muS[tid] = 0.f; rsS[tid] = rsqrtf(1e-3f); }

    v8hf wR[16], wK[16];
    {
        const int col = (wv << 9) + u0 + rr;
        float sb = 0.f;
#pragma unroll
        for (int kk = 0; kk < 16; ++kk) {
#pragma unroll
            for (int j = 0; j < 8; ++j) {
                int k = (kk << 5) + kb + j;
                float wr = Wr1[(size_t)k * 2048 + col];
                float wk = Wk1[(size_t)k * 2048 + col];
                wR[kk][j] = (_Float16)wr;
                wK[kk][j] = (_Float16)(gamma[k] * wk);
                sb += beta[k] * wk;
            }
        }
        sb += __shfl_xor(sb, 16); sb += __shfl_xor(sb, 32);
        if (lane < 16)
            ((float*)(sm + B1OFF))[(wv << 4) + lane] = b1[(wv << 9) + u0 + lane] + sb;
    }

    const int r_ep = tid >> 4, q_ep = tid & 15;
    const int len_r = lens[(g << 4) + r_ep];
    const int ml = gmax[g];
    unsigned* slotg = slots + (g << 9);            // 32 slots x 64B stride per group
    uint16_t* h1g = h1all + (size_t)g * 4194304;
    float c0 = 0.f, c1 = 0.f;
    const int hob = ((r_ep << 10) + ((u0 + q_ep) << 1)) ^ ((r_ep & 7) << 4);
    float px0, px1, px2;
    { const float* xp = x + ((size_t)((g << 4) + r_ep) * 512) * 3;
      px0 = xp[0]; px1 = xp[1]; px2 = xp[2]; }
    __syncthreads();

    for (int t = 0;; ++t) {
        // ---- 3 MFMA chains: z0 = P0@Wr0, z1 = LNreg(P0)@(g.*Wk1) + P1@Wr1 ----
        const float mu_r = muS[rr], rs_r = rsS[rr];
        v4f acc0 = {0,0,0,0}, accK = {0,0,0,0}, accR = {0,0,0,0};
#pragma unroll
        for (int kk = 0; kk < 16; ++kk) {
            int k = kb + (kk << 5);
            int ab = ((rr << 10) + (k << 1)) ^ ((rr & 7) << 4);
            v8hf a0 = *(const v8hf*)(sm + P0OFF + ab);
            int jr = (wv << 4) + rr;
            int bb = ((jr << 10) + (k << 1)) ^ ((jr & 7) << 4);
            v8hf bf = *(const v8hf*)(sm + bb);
            acc0 = __builtin_amdgcn_mfma_f32_16x16x32_f16(a0, bf, acc0, 0, 0, 0);
            v8hf an;
#pragma unroll
            for (int j = 0; j < 8; ++j) an[j] = (_Float16)(((float)a0[j] - mu_r) * rs_r);
            accK = __builtin_amdgcn_mfma_f32_16x16x32_f16(an, wK[kk], accK, 0, 0, 0);
            v8hf a1 = *(const v8hf*)(sm + P1OFF + ab);
            accR = __builtin_amdgcn_mfma_f32_16x16x32_f16(a1, wR[kk], accR, 0, 0, 0);
        }
        {
            float* z0f = (float*)(sm + Z0OFF);
            float* z1f = (float*)(sm + Z1OFF);
            int j = (wv << 4) + rr;
#pragma unroll
            for (int jj = 0; jj < 4; ++jj) {
                int m = (hq << 2) + jj;
                int w = ((m << 6) + j) ^ ((m & 7) << 2);
                z0f[w] = acc0[jj]; z1f[w] = accR[jj] + accK[jj];
            }
        }
        float hold0 = h2f(*(const uint16_t*)(sm + P0OFF + hob));
        float hold1 = h2f(*(const uint16_t*)(sm + P1OFF + hob));
        __syncthreads();

        // ---- gates; h published via agent-relaxed atomic u32 stores (IC-homed) ----
        const float* b1s = (const float*)(sm + B1OFF);
        const float* wks = (const float*)(sm + WKOFF);
        const float* b0s = (const float*)(sm + B0OFF);
        if (t < ml) {   // layer-0 step t
            float zg[4];
#pragma unroll
            for (int G = 0; G < 4; ++G) {
                int j = (G << 4) + q_ep;
                int w = ((r_ep << 6) + j) ^ ((r_ep & 7) << 2);
                zg[G] = ((const float*)(sm + Z0OFF))[w]
                      + px0 * wks[j] + px1 * wks[64 + j] + px2 * wks[128 + j] + b0s[j];
            }
            float si = 1.f/(1.f+__expf(-zg[0])), sf = 1.f/(1.f+__expf(-zg[1]));
            float tg = tanhf(zg[2]), so = 1.f/(1.f+__expf(-zg[3]));
            float cn = sf * c0 + si * tg;
            float hn = so * tanhf(cn);
            if (t < len_r) c0 = cn; else hn = hold0;
            unsigned hu = f2h(hn);
            unsigned pr = __shfl_xor(hu, 1);
            if (!(q_ep & 1)) {
                size_t idx = (size_t)((((t + 1) & 1) << 3) + g) * 8192 + (r_ep << 9) + u0 + q_ep;
                __hip_atomic_store((unsigned*)(h0buf + idx), hu | (pr << 16),
                                   __ATOMIC_RELAXED, __HIP_MEMORY_SCOPE_AGENT);
            }
        }
        if (t >= 1) {   // layer-1 step t-1
            float zg[4];
#pragma unroll
            for (int G = 0; G < 4; ++G) {
                int j = (G << 4) + q_ep;
                int w = ((r_ep << 6) + j) ^ ((r_ep & 7) << 2);
                zg[G] = ((const float*)(sm + Z1OFF))[w] + b1s[j];
            }
            float si = 1.f/(1.f+__expf(-zg[0])), sf = 1.f/(1.f+__expf(-zg[1]));
            float tg = tanhf(zg[2]), so = 1.f/(1.f+__expf(-zg[3]));
            float cn = sf * c1 + si * tg;
            float hn = so * tanhf(cn);
            if (t - 1 < len_r) c1 = cn; else hn = hold1;
            unsigned hu = f2h(hn);
            unsigned pr = __shfl_xor(hu, 1);
            if (!(q_ep & 1)) {
                size_t idx = (size_t)(t - 1) * 8192 + (r_ep << 9) + u0 + q_ep;
                __hip_atomic_store((unsigned*)(h1g + idx), hu | (pr << 16),
                                   __ATOMIC_RELAXED, __HIP_MEMORY_SCOPE_AGENT);
            }
        }
        if (t == ml) break;
        __syncthreads();                     // barrier drains vmcnt: atomic stores ACKed

        // ---- release: bump own slot (RMW at IC) ----
        if (tid == 0) {
            asm volatile("s_waitcnt vmcnt(0)" ::: "memory");
            __hip_atomic_fetch_add(slotg + (cs << 4), 1u,
                                   __ATOMIC_RELAXED, __HIP_MEMORY_SCOPE_AGENT);
        }
        // off critical path: prefetch x[t+1] into registers
        { int tn = (t + 1 < ml) ? t + 1 : ml - 1;
          const float* xp = x + ((size_t)((g << 4) + r_ep) * 512 + tn) * 3;
          px0 = xp[0]; px1 = xp[1]; px2 = xp[2]; }
        // ---- wait: 32 lanes poll 32 slots with agent-relaxed loads (R2-proven) ----
        if (tid < 32) {
            const unsigned tgt = (unsigned)(t + 1);
            const unsigned* sp = slotg + (tid << 4);
            long guard = 0;
            for (;;) {
                unsigned v = __hip_atomic_load(sp, __ATOMIC_RELAXED, __HIP_MEMORY_SCOPE_AGENT);
                if ((__ballot(v >= tgt) & 0xFFFFFFFFull) == 0xFFFFFFFFull) break;
                __builtin_amdgcn_s_sleep(1);
                if (++guard > 1000000L) break;   // ~0.3s loud failure, no hang
            }
            asm volatile("s_waitcnt vmcnt(0)" ::: "memory");
        }
        __syncthreads();
        // ---- stage next tiles through IC: P0 <- h0[t] (+LN stats), P1 <- h1[t-1] ----
        stage_tile_ic(h0buf + (size_t)((((t + 1) & 1) << 3) + g) * 8192, sm, P0OFF, muS, rsS, 1);
        if (t >= 1) stage_tile_ic(h1g + (size_t)(t - 1) * 8192, sm, P1OFF, muS, rsS, 0);
        __syncthreads();
    }
}

// Trailing kernel: out[b,t] = softmax(LN(h1[min(t,ml-1)]) @ Wfc + bfc). One wave per (b,t).
__global__ __launch_bounds__(256) void finalize(
    const uint16_t* __restrict__ h1all, const int* __restrict__ gmax,
    const float* __restrict__ gamma, const float* __restrict__ beta,
    const float* __restrict__ Wfc, const float* __restrict__ bfc,
    float* __restrict__ out)
{
    int wv = threadIdx.x >> 6, lane = threadIdx.x & 63;
    int rid = blockIdx.x * 4 + wv;
    int b = rid >> 9, t = rid & 511;
    int g = b >> 4, r = b & 15;
    int ml = gmax[g];
    int ts = t < ml ? t : ml - 1;
    const uint16_t* hp = h1all + (size_t)g * 4194304 + (size_t)ts * 8192 + (r << 9) + (lane << 3);
    v8hf h8 = *(const v8hf*)hp;
    float hv[8]; float s = 0.f, q2 = 0.f;
#pragma unroll
    for (int j = 0; j < 8; ++j) { float f = (float)h8[j]; hv[j] = f; s += f; q2 += f * f; }
#pragma unroll
    for (int m = 1; m < 64; m <<= 1) { s += __shfl_xor(s, m); q2 += __shfl_xor(q2, m); }
    float mu = s * (1.f / 512.f);
    float rstd = rsqrtf(q2 * (1.f / 512.f) - mu * mu + 1e-3f);
    float p0=0,p1=0,p2=0,p3=0,p4=0;
#pragma unroll
    for (int j = 0; j < 8; ++j) {
        int k = (lane << 3) + j;
        float hn = (hv[j] - mu) * rstd * gamma[k] + beta[k];
        const float* wf = Wfc + (size_t)k * 5;
        p0 += hn*wf[0]; p1 += hn*wf[1]; p2 += hn*wf[2]; p3 += hn*wf[3]; p4 += hn*wf[4];
    }
#pragma unroll
    for (int m = 1; m < 64; m <<= 1) {
        p0 += __shfl_xor(p0,m); p1 += __shfl_xor(p1,m); p2 += __shfl_xor(p2,m);
        p3 += __shfl_xor(p3,m); p4 += __shfl_xor(p4,m);
    }
    if (lane == 0) {
        float l0=p0+bfc[0], l1=p1+bfc[1], l2=p2+bfc[2], l3=p3+bfc[3], l4=p4+bfc[4];
        float mx = fmaxf(fmaxf(fmaxf(l0,l1),fmaxf(l2,l3)),l4);
        float e0=__expf(l0-mx), e1=__expf(l1-mx), e2=__expf(l2-mx), e3=__expf(l3-mx), e4=__expf(l4-mx);
        float inv = 1.f/(e0+e1+e2+e3+e4);
        float* op = out + (size_t)rid * 5;
        op[0]=e0*inv; op[1]=e1*inv; op[2]=e2*inv; op[3]=e3*inv; op[4]=e4*inv;
    }
}

extern "C" void kernel_launch(void* const* d_in, const int* in_sizes, int n_in,
                              void* d_out, int out_size, void* d_ws, size_t ws_size,
                              hipStream_t stream) {
    (void)in_sizes; (void)n_in; (void)out_size;
    const float* x     = (const float*)d_in[0];
    const void*  mask  = d_in[1];
    const float* Wk0   = (const float*)d_in[2];
    const float* Wr0   = (const float*)d_in[3];
    const float* b0    = (const float*)d_in[4];
    const float* Wk1   = (const float*)d_in[5];
    const float* Wr1   = (const float*)d_in[6];
    const float* b1    = (const float*)d_in[7];
    const float* gamma = (const float*)d_in[8];
    const float* beta  = (const float*)d_in[9];
    const float* Wfc   = (const float*)d_in[10];
    const float* bfc   = (const float*)d_in[11];
    float* out = (float*)d_out;
    char* ws = (char*)d_ws;
    unsigned* slots = (unsigned*)(ws);             // 8 groups x 32 slots x 64B = 16KB
    int*      lens  = (int*)(ws + 16384);          // 128 ints
    int*      gmax  = (int*)(ws + 16896);          // 8 ints
    uint16_t* h0buf = (uint16_t*)(ws + 32768);     // 2 x 8 x 16KB = 256KB
    uint16_t* h1all = (uint16_t*)(ws + 294912);    // 8 x 512 x 16KB = 64MB
    if (ws_size < 67403776) return;

    hipFuncSetAttribute((const void*)lstm_merged, hipFuncAttributeMaxDynamicSharedMemorySize, LDSSZ);
    hipMemsetAsync(ws, 0, 32768, stream);   // slots/lens/gmax zeroed every call
    setup_lens<<<128, 64, 0, stream>>>(mask, lens, gmax);
    lstm_merged<<<256, 256, LDSSZ, stream>>>(x, Wk0, Wr0, b0, Wk1, Wr1, b1, gamma, beta,
                                             lens, gmax, slots, h0buf, h1all);
    finalize<<<16384, 256, 0, stream>>>(h1all, gmax, gamma, beta, Wfc, bfc, out);
}